// Round 6
// baseline (446.572 us; speedup 1.0000x reference)
//
#include <hip/hip_runtime.h>
#include <float.h>

#define N_ROWS 131072
#define DIM 64
#define KCODES 1024
#define TAU 1.0e-3f
#define AMB_MAX 32768
#define BLOCKC 256
#define NBLOCKC (N_ROWS / BLOCKC)   // 512
#define BLOCKE 256                  // exact pass: one block per ambiguous row

typedef __attribute__((ext_vector_type(8))) short short8;
typedef __attribute__((ext_vector_type(4))) float f32x4;

// bf16 round-to-nearest-even split helpers
__device__ __forceinline__ unsigned short f2bf_rne(float x) {
    unsigned int u = __float_as_uint(x);
    unsigned int r = u + 0x7FFFu + ((u >> 16) & 1u);
    return (unsigned short)(r >> 16);
}
__device__ __forceinline__ float bf2f(unsigned short h) {
    return __uint_as_float(((unsigned int)h) << 16);
}

// numpy pairwise sum of squares over 64 floats (bit-exact vs np.sum(v*v))
__device__ __forceinline__ float np_pairwise_sq64(const float* v) {
    float r[8];
#pragma unroll
    for (int j = 0; j < 8; ++j) r[j] = __fmul_rn(v[j], v[j]);
#pragma unroll
    for (int i = 8; i < 64; i += 8)
#pragma unroll
        for (int j = 0; j < 8; ++j)
            r[j] = __fadd_rn(r[j], __fmul_rn(v[i + j], v[i + j]));
    return __fadd_rn(
        __fadd_rn(__fadd_rn(r[0], r[1]), __fadd_rn(r[2], r[3])),
        __fadd_rn(__fadd_rn(r[4], r[5]), __fadd_rn(r[6], r[7])));
}

// ---------------------------------------------------------------------------
// Prep: zero hist/amb, np-exact b_sq, and pack E as bf16 hi/lo in MFMA
// frag order: epack[ct(64)][lvl(2)][kt(2)][lane(64)][j(8)] ushort.
// ---------------------------------------------------------------------------
__global__ void vq_prep(const float* __restrict__ emb,
                        int* __restrict__ hist,
                        float* __restrict__ bsqf,
                        int* __restrict__ amb_count,
                        unsigned short* __restrict__ epack) {
    int c = blockIdx.x * blockDim.x + threadIdx.x;   // 0..1023
    if (c == 0) *amb_count = 0;
    if (c >= KCODES) return;
    hist[c] = 0;
    float e[DIM];
    const float4* src = reinterpret_cast<const float4*>(emb + (size_t)c * DIM);
#pragma unroll
    for (int i = 0; i < DIM / 4; ++i) {
        float4 v = src[i];
        e[i * 4 + 0] = v.x; e[i * 4 + 1] = v.y;
        e[i * 4 + 2] = v.z; e[i * 4 + 3] = v.w;
    }
    bsqf[c] = np_pairwise_sq64(e);

    const int ct = c >> 4, col = c & 15;
#pragma unroll
    for (int k = 0; k < DIM; ++k) {
        unsigned short h = f2bf_rne(e[k]);
        unsigned short l = f2bf_rne(e[k] - bf2f(h));
        int kt = k >> 5;
        int lane = (((k & 31) >> 3) << 4) | col;
        int j = k & 7;
        epack[(((size_t)(ct * 2 + 0) * 2 + kt) * 64 + lane) * 8 + j] = h;
        epack[(((size_t)(ct * 2 + 1) * 2 + kt) * 64 + lane) * 8 + j] = l;
    }
}

// ---------------------------------------------------------------------------
// Pass A: MFMA scorer (validated). Wave owns 64 rows; 3-term bf16 hi/lo dot;
// best/sec/idx tracked per lane, cross-lane reduce over lane&15.
// ---------------------------------------------------------------------------
__global__ __launch_bounds__(256, 2)
void vq_fast(const float* __restrict__ x,
             const unsigned short* __restrict__ epack,
             const float* __restrict__ bsqf,
             float* __restrict__ idxout,
             int* __restrict__ amb_count,
             int* __restrict__ amb_list) {
    __shared__ unsigned short lds[32768];   // 64 KiB = 16 code-tiles

    const int t = threadIdx.x;
    const int lane = t & 63;
    const int wid = t >> 6;
    const int rowbase = (blockIdx.x * 4 + wid) * 64;
    const int arow = lane & 15;
    const int kgrp = lane >> 4;

    short8 ah[4][2], al[4][2];
#pragma unroll
    for (int mf = 0; mf < 4; ++mf) {
#pragma unroll
        for (int kt = 0; kt < 2; ++kt) {
            const float* src = x + (size_t)(rowbase + mf * 16 + arow) * DIM + kt * 32 + kgrp * 8;
            float4 v0 = *reinterpret_cast<const float4*>(src);
            float4 v1 = *reinterpret_cast<const float4*>(src + 4);
            float xv[8] = {v0.x, v0.y, v0.z, v0.w, v1.x, v1.y, v1.z, v1.w};
            short8 h, l;
#pragma unroll
            for (int j = 0; j < 8; ++j) {
                unsigned short hh = f2bf_rne(xv[j]);
                h[j] = (short)hh;
                l[j] = (short)f2bf_rne(xv[j] - bf2f(hh));
            }
            ah[mf][kt] = h;
            al[mf][kt] = l;
        }
    }

    float best[4][4], sec[4][4];
    int bidx[4][4];
#pragma unroll
    for (int mf = 0; mf < 4; ++mf)
#pragma unroll
        for (int r = 0; r < 4; ++r) {
            best[mf][r] = FLT_MAX; sec[mf][r] = FLT_MAX; bidx[mf][r] = 0;
        }

    for (int ch = 0; ch < 4; ++ch) {
        __syncthreads();
        {   // stage 64KB chunk: 4096 float4, 16 per thread, coalesced
            const float4* gsrc = reinterpret_cast<const float4*>(epack + (size_t)ch * 32768);
            float4* ldst = reinterpret_cast<float4*>(lds);
#pragma unroll
            for (int i = 0; i < 16; ++i)
                ldst[t + i * 256] = gsrc[t + i * 256];
        }
        __syncthreads();

        for (int ctl = 0; ctl < 16; ++ctl) {
            const int code0 = (ch * 16 + ctl) * 16;
            const unsigned short* fb = lds + ctl * 2048 + lane * 8;
            short8 bh0 = *reinterpret_cast<const short8*>(fb + 0 * 512);
            short8 bh1 = *reinterpret_cast<const short8*>(fb + 1 * 512);
            short8 bl0 = *reinterpret_cast<const short8*>(fb + 2 * 512);
            short8 bl1 = *reinterpret_cast<const short8*>(fb + 3 * 512);
            const float bq = bsqf[code0 + arow];

            f32x4 acc[4];
#pragma unroll
            for (int mf = 0; mf < 4; ++mf) {
                f32x4 a = {0.f, 0.f, 0.f, 0.f};
                a = __builtin_amdgcn_mfma_f32_16x16x32_bf16(ah[mf][0], bh0, a, 0, 0, 0);
                a = __builtin_amdgcn_mfma_f32_16x16x32_bf16(ah[mf][1], bh1, a, 0, 0, 0);
                a = __builtin_amdgcn_mfma_f32_16x16x32_bf16(ah[mf][0], bl0, a, 0, 0, 0);
                a = __builtin_amdgcn_mfma_f32_16x16x32_bf16(ah[mf][1], bl1, a, 0, 0, 0);
                a = __builtin_amdgcn_mfma_f32_16x16x32_bf16(al[mf][0], bh0, a, 0, 0, 0);
                a = __builtin_amdgcn_mfma_f32_16x16x32_bf16(al[mf][1], bh1, a, 0, 0, 0);
                acc[mf] = a;
            }

            const int code = code0 + arow;   // C col = lane&15 [m89/m91]
#pragma unroll
            for (int mf = 0; mf < 4; ++mf)
#pragma unroll
                for (int r = 0; r < 4; ++r) {
                    float s = fmaf(-2.0f, acc[mf][r], bq);
                    sec[mf][r] = fminf(sec[mf][r], fmaxf(s, best[mf][r]));
                    bidx[mf][r] = (s < best[mf][r]) ? code : bidx[mf][r];
                    best[mf][r] = fminf(best[mf][r], s);
                }
        }
    }

    // cross-lane argmin over the 16 col-classes (lane&15); row preserved
#pragma unroll
    for (int mf = 0; mf < 4; ++mf)
#pragma unroll
        for (int r = 0; r < 4; ++r) {
            float b = best[mf][r], sc = sec[mf][r];
            int id = bidx[mf][r];
#pragma unroll
            for (int off = 1; off < 16; off <<= 1) {
                float ob = __shfl_xor(b, off);
                float osc = __shfl_xor(sc, off);
                int oi = __shfl_xor(id, off);
                float nsec = fminf(fminf(sc, osc), fmaxf(b, ob));
                id = (ob < b) ? oi : id;
                b = fminf(b, ob);
                sc = nsec;
            }
            best[mf][r] = b; sec[mf][r] = sc; bidx[mf][r] = id;
        }

    if ((lane & 15) == 0) {
        const int rgrp = lane >> 4;   // C row = (lane>>4)*4 + reg [m89/m91]
#pragma unroll
        for (int mf = 0; mf < 4; ++mf)
#pragma unroll
            for (int r = 0; r < 4; ++r) {
                int row = rowbase + mf * 16 + rgrp * 4 + r;
                idxout[row] = (float)bidx[mf][r];
                if (sec[mf][r] - best[mf][r] <= TAU) {
                    int p = atomicAdd(amb_count, 1);
                    if (p < AMB_MAX) amb_list[p] = row;
                }
            }
    }
}

// ---------------------------------------------------------------------------
// Pass B: exact rescan — ONE BLOCK PER AMBIGUOUS ROW, one code per thread
// (x4). Validated chain: np-pairwise a_sq/b_sq fp32, fp64 dot, fl32 combine,
// ties -> lower index. Shared-memory tree argmin.
// ---------------------------------------------------------------------------
__global__ __launch_bounds__(BLOCKE, 4)
void vq_exact(const float* __restrict__ x,
              const float* __restrict__ emb,
              const float* __restrict__ bsqf,
              const int* __restrict__ amb_count,
              const int* __restrict__ amb_list,
              float* __restrict__ idxout) {
    __shared__ float sd[BLOCKE];
    __shared__ int   si[BLOCKE];
    const int t = threadIdx.x;
    int cnt = *amb_count;
    if (cnt > AMB_MAX) cnt = AMB_MAX;

    for (int i = blockIdx.x; i < cnt; i += gridDim.x) {
        __syncthreads();
        const int row = amb_list[i];

        // broadcast-load the row; a_sq via the bit-exact numpy scheme
        float af[DIM];
        const float4* xr = reinterpret_cast<const float4*>(x + (size_t)row * DIM);
#pragma unroll
        for (int j = 0; j < DIM / 4; ++j) {
            float4 v = xr[j];
            af[j * 4 + 0] = v.x; af[j * 4 + 1] = v.y;
            af[j * 4 + 2] = v.z; af[j * 4 + 3] = v.w;
        }
        const float a_sq = np_pairwise_sq64(af);

        float best = FLT_MAX;
        int bidx = KCODES;
#pragma unroll
        for (int cc = 0; cc < KCODES / BLOCKE; ++cc) {
            const int c = t + cc * BLOCKE;   // increasing -> '<' keeps first
            const float* e = emb + (size_t)c * DIM;
            double acc0 = 0.0, acc1 = 0.0, acc2 = 0.0, acc3 = 0.0;
#pragma unroll
            for (int d = 0; d < DIM; d += 4) {
                float4 ev = *reinterpret_cast<const float4*>(e + d);
                acc0 = fma((double)af[d + 0], (double)ev.x, acc0);
                acc1 = fma((double)af[d + 1], (double)ev.y, acc1);
                acc2 = fma((double)af[d + 2], (double)ev.z, acc2);
                acc3 = fma((double)af[d + 3], (double)ev.w, acc3);
            }
            double dot = (acc0 + acc1) + (acc2 + acc3);
            float ab = (float)(2.0 * dot);
            float dist = __fadd_rn(__fsub_rn(a_sq, ab), bsqf[c]);
            if (dist < best) { best = dist; bidx = c; }
        }

        sd[t] = best; si[t] = bidx;
        __syncthreads();
        for (int off = BLOCKE / 2; off > 0; off >>= 1) {
            if (t < off) {
                float d2 = sd[t + off]; int i2 = si[t + off];
                if (d2 < sd[t] || (d2 == sd[t] && i2 < si[t])) {
                    sd[t] = d2; si[t] = i2;
                }
            }
            __syncthreads();
        }
        if (t == 0) idxout[row] = (float)si[0];
    }
}

// ---------------------------------------------------------------------------
// Pass C: finalize — gather quantized rows, histogram, deterministic loss.
// ---------------------------------------------------------------------------
__global__ __launch_bounds__(BLOCKC, 2)
void vq_finalize(const float* __restrict__ x,
                 const float* __restrict__ emb,
                 const float* __restrict__ idxout,
                 float* __restrict__ qout,
                 int* __restrict__ hist,
                 float* __restrict__ partials) {
    __shared__ float red[BLOCKC];
    const int row = blockIdx.x * BLOCKC + threadIdx.x;
    const int k = (int)idxout[row];

    const float4* xr = reinterpret_cast<const float4*>(x + (size_t)row * DIM);
    const float4* q  = reinterpret_cast<const float4*>(emb + (size_t)k * DIM);
    float4* qo = reinterpret_cast<float4*>(qout + (size_t)row * DIM);

    float lsum0 = 0.f, lsum1 = 0.f;
#pragma unroll
    for (int i = 0; i < DIM / 4; ++i) {
        float4 v = q[i];
        float4 a = xr[i];
        qo[i] = v;
        float dx = v.x - a.x, dy = v.y - a.y;
        float dz = v.z - a.z, dw = v.w - a.w;
        lsum0 = fmaf(dx, dx, lsum0);
        lsum1 = fmaf(dy, dy, lsum1);
        lsum0 = fmaf(dz, dz, lsum0);
        lsum1 = fmaf(dw, dw, lsum1);
    }
    atomicAdd(&hist[k], 1);

    __syncthreads();
    red[threadIdx.x] = lsum0 + lsum1;
    __syncthreads();
    for (int off = BLOCKC / 2; off > 0; off >>= 1) {
        if (threadIdx.x < off) red[threadIdx.x] += red[threadIdx.x + off];
        __syncthreads();
    }
    if (threadIdx.x == 0) partials[blockIdx.x] = red[0];
}

// ---------------------------------------------------------------------------
// Final: perplexity (fp64) + loss reduction.
// ---------------------------------------------------------------------------
__global__ void vq_final(const int* __restrict__ hist,
                         const float* __restrict__ partials,
                         float* __restrict__ out2) {
    __shared__ double sh[KCODES];
    __shared__ float sl[NBLOCKC];
    int t = threadIdx.x;

    double p = (double)hist[t] * (1.0 / (double)N_ROWS);
    sh[t] = p * log(p + 1e-10);
    if (t < NBLOCKC) sl[t] = partials[t];
    __syncthreads();

    for (int off = KCODES / 2; off > 0; off >>= 1) {
        if (t < off) sh[t] += sh[t + off];
        __syncthreads();
    }
    for (int off = NBLOCKC / 2; off > 0; off >>= 1) {
        if (t < off) sl[t] += sl[t + off];
        __syncthreads();
    }
    if (t == 0) {
        out2[0] = (float)exp(-sh[0]);
        out2[1] = 1.25f * sl[0] * (1.0f / (float)(N_ROWS * DIM));
    }
}

// ---------------------------------------------------------------------------
extern "C" void kernel_launch(void* const* d_in, const int* in_sizes, int n_in,
                              void* d_out, int out_size, void* d_ws, size_t ws_size,
                              hipStream_t stream) {
    const float* x   = (const float*)d_in[0];   // [131072, 64]
    const float* emb = (const float*)d_in[1];   // [1024, 64]
    float* out = (float*)d_out;

    // ws: hist[1024]@0 | bsqf[1024]@4096 | partials[512]@8192 |
    //     amb_count@10240 | amb_list[32768]@12288 | epack@143360 (256KB)
    int*   hist      = (int*)d_ws;
    float* bsqf      = (float*)((char*)d_ws + 4096);
    float* partials  = (float*)((char*)d_ws + 8192);
    int*   amb_count = (int*)((char*)d_ws + 10240);
    int*   amb_list  = (int*)((char*)d_ws + 12288);
    unsigned short* epack = (unsigned short*)((char*)d_ws + 143360);

    float* qout    = out;                       // 8388608
    float* idxout  = out + 8388608;             // 131072
    float* scalars = out + 8388608 + 131072;    // perplexity, vq_loss

    vq_prep    <<<KCODES / 256, 256, 0, stream>>>(emb, hist, bsqf, amb_count, epack);
    vq_fast    <<<N_ROWS / 256, 256, 0, stream>>>(x, epack, bsqf, idxout, amb_count, amb_list);
    vq_exact   <<<2048, BLOCKE, 0, stream>>>(x, emb, bsqf, amb_count, amb_list, idxout);
    vq_finalize<<<NBLOCKC, BLOCKC, 0, stream>>>(x, emb, idxout, qout, hist, partials);
    vq_final   <<<1, KCODES, 0, stream>>>(hist, partials, scalars);
}

// Round 7
// 136.476 us; speedup vs baseline: 3.2722x; 3.2722x over previous
//
#include <hip/hip_runtime.h>
#include <float.h>

#define N_ROWS 131072
#define DIM 64
#define KCODES 1024
#define TAU 1.0e-3f
#define AMB_MAX 32768
#define BLOCKC 256
#define NBLOCKC (N_ROWS / BLOCKC)   // 512

typedef __attribute__((ext_vector_type(8))) short short8;
typedef __attribute__((ext_vector_type(4))) float f32x4;

// bf16 round-to-nearest-even split helpers
__device__ __forceinline__ unsigned short f2bf_rne(float x) {
    unsigned int u = __float_as_uint(x);
    unsigned int r = u + 0x7FFFu + ((u >> 16) & 1u);
    return (unsigned short)(r >> 16);
}
__device__ __forceinline__ float bf2f(unsigned short h) {
    return __uint_as_float(((unsigned int)h) << 16);
}

// numpy pairwise sum of squares over 64 floats (bit-exact vs np.sum(v*v))
__device__ __forceinline__ float np_pairwise_sq64(const float* v) {
    float r[8];
#pragma unroll
    for (int j = 0; j < 8; ++j) r[j] = __fmul_rn(v[j], v[j]);
#pragma unroll
    for (int i = 8; i < 64; i += 8)
#pragma unroll
        for (int j = 0; j < 8; ++j)
            r[j] = __fadd_rn(r[j], __fmul_rn(v[i + j], v[i + j]));
    return __fadd_rn(
        __fadd_rn(__fadd_rn(r[0], r[1]), __fadd_rn(r[2], r[3])),
        __fadd_rn(__fadd_rn(r[4], r[5]), __fadd_rn(r[6], r[7])));
}

// exact reference-chain distance for one (row, code):
// d = fl32( fl32(a_sq - fl32(2*dot_f64)) + b_sq )   [validated rounds 3-6]
__device__ __forceinline__ float np_dist(const float* af, float a_sq,
                                         const float* e, float bq) {
    double acc0 = 0.0, acc1 = 0.0, acc2 = 0.0, acc3 = 0.0;
#pragma unroll
    for (int d = 0; d < DIM; d += 4) {
        float4 ev = *reinterpret_cast<const float4*>(e + d);
        acc0 = fma((double)af[d + 0], (double)ev.x, acc0);
        acc1 = fma((double)af[d + 1], (double)ev.y, acc1);
        acc2 = fma((double)af[d + 2], (double)ev.z, acc2);
        acc3 = fma((double)af[d + 3], (double)ev.w, acc3);
    }
    double dot = (acc0 + acc1) + (acc2 + acc3);
    float ab = (float)(2.0 * dot);
    return __fadd_rn(__fsub_rn(a_sq, ab), bq);
}

// ---------------------------------------------------------------------------
// Prep: zero hist/amb, np-exact b_sq, pack E as bf16 hi/lo in MFMA frag order.
// ---------------------------------------------------------------------------
__global__ void vq_prep(const float* __restrict__ emb,
                        int* __restrict__ hist,
                        float* __restrict__ bsqf,
                        int* __restrict__ amb_count,
                        unsigned short* __restrict__ epack) {
    int c = blockIdx.x * blockDim.x + threadIdx.x;   // 0..1023
    if (c == 0) *amb_count = 0;
    if (c >= KCODES) return;
    hist[c] = 0;
    float e[DIM];
    const float4* src = reinterpret_cast<const float4*>(emb + (size_t)c * DIM);
#pragma unroll
    for (int i = 0; i < DIM / 4; ++i) {
        float4 v = src[i];
        e[i * 4 + 0] = v.x; e[i * 4 + 1] = v.y;
        e[i * 4 + 2] = v.z; e[i * 4 + 3] = v.w;
    }
    bsqf[c] = np_pairwise_sq64(e);

    const int ct = c >> 4, col = c & 15;
#pragma unroll
    for (int k = 0; k < DIM; ++k) {
        unsigned short h = f2bf_rne(e[k]);
        unsigned short l = f2bf_rne(e[k] - bf2f(h));
        int kt = k >> 5;
        int lane = (((k & 31) >> 3) << 4) | col;
        int j = k & 7;
        epack[(((size_t)(ct * 2 + 0) * 2 + kt) * 64 + lane) * 8 + j] = h;
        epack[(((size_t)(ct * 2 + 1) * 2 + kt) * 64 + lane) * 8 + j] = l;
    }
}

// ---------------------------------------------------------------------------
// Pass A: MFMA scorer. Tracks best AND second-best with indices; flagged rows
// (gap <= TAU) emit (row, candidate-pair) for the exact pair-fix.
// ---------------------------------------------------------------------------
__global__ __launch_bounds__(256, 2)
void vq_fast(const float* __restrict__ x,
             const unsigned short* __restrict__ epack,
             const float* __restrict__ bsqf,
             float* __restrict__ idxout,
             int* __restrict__ amb_count,
             int* __restrict__ amb_rows,
             int* __restrict__ amb_cand) {
    __shared__ unsigned short lds[32768];   // 64 KiB = 16 code-tiles

    const int t = threadIdx.x;
    const int lane = t & 63;
    const int wid = t >> 6;
    const int rowbase = (blockIdx.x * 4 + wid) * 64;
    const int arow = lane & 15;
    const int kgrp = lane >> 4;

    short8 ah[4][2], al[4][2];
#pragma unroll
    for (int mf = 0; mf < 4; ++mf) {
#pragma unroll
        for (int kt = 0; kt < 2; ++kt) {
            const float* src = x + (size_t)(rowbase + mf * 16 + arow) * DIM + kt * 32 + kgrp * 8;
            float4 v0 = *reinterpret_cast<const float4*>(src);
            float4 v1 = *reinterpret_cast<const float4*>(src + 4);
            float xv[8] = {v0.x, v0.y, v0.z, v0.w, v1.x, v1.y, v1.z, v1.w};
            short8 h, l;
#pragma unroll
            for (int j = 0; j < 8; ++j) {
                unsigned short hh = f2bf_rne(xv[j]);
                h[j] = (short)hh;
                l[j] = (short)f2bf_rne(xv[j] - bf2f(hh));
            }
            ah[mf][kt] = h;
            al[mf][kt] = l;
        }
    }

    float best[4][4], sec[4][4];
    int bidx[4][4], sidx[4][4];
#pragma unroll
    for (int mf = 0; mf < 4; ++mf)
#pragma unroll
        for (int r = 0; r < 4; ++r) {
            best[mf][r] = FLT_MAX; sec[mf][r] = FLT_MAX;
            bidx[mf][r] = 0; sidx[mf][r] = 0;
        }

    for (int ch = 0; ch < 4; ++ch) {
        __syncthreads();
        {   // stage 64KB chunk: 4096 float4, 16 per thread, coalesced
            const float4* gsrc = reinterpret_cast<const float4*>(epack + (size_t)ch * 32768);
            float4* ldst = reinterpret_cast<float4*>(lds);
#pragma unroll
            for (int i = 0; i < 16; ++i)
                ldst[t + i * 256] = gsrc[t + i * 256];
        }
        __syncthreads();

        for (int ctl = 0; ctl < 16; ++ctl) {
            const int code0 = (ch * 16 + ctl) * 16;
            const unsigned short* fb = lds + ctl * 2048 + lane * 8;
            short8 bh0 = *reinterpret_cast<const short8*>(fb + 0 * 512);
            short8 bh1 = *reinterpret_cast<const short8*>(fb + 1 * 512);
            short8 bl0 = *reinterpret_cast<const short8*>(fb + 2 * 512);
            short8 bl1 = *reinterpret_cast<const short8*>(fb + 3 * 512);
            const float bq = bsqf[code0 + arow];

            f32x4 acc[4];
#pragma unroll
            for (int mf = 0; mf < 4; ++mf) {
                f32x4 a = {0.f, 0.f, 0.f, 0.f};
                a = __builtin_amdgcn_mfma_f32_16x16x32_bf16(ah[mf][0], bh0, a, 0, 0, 0);
                a = __builtin_amdgcn_mfma_f32_16x16x32_bf16(ah[mf][1], bh1, a, 0, 0, 0);
                a = __builtin_amdgcn_mfma_f32_16x16x32_bf16(ah[mf][0], bl0, a, 0, 0, 0);
                a = __builtin_amdgcn_mfma_f32_16x16x32_bf16(ah[mf][1], bl1, a, 0, 0, 0);
                a = __builtin_amdgcn_mfma_f32_16x16x32_bf16(al[mf][0], bh0, a, 0, 0, 0);
                a = __builtin_amdgcn_mfma_f32_16x16x32_bf16(al[mf][1], bh1, a, 0, 0, 0);
                acc[mf] = a;
            }

            const int code = code0 + arow;   // C col = lane&15 [m89/m91]
#pragma unroll
            for (int mf = 0; mf < 4; ++mf)
#pragma unroll
                for (int r = 0; r < 4; ++r) {
                    float s = fmaf(-2.0f, acc[mf][r], bq);
                    bool lt_b = s < best[mf][r];
                    bool lt_s = s < sec[mf][r];
                    sec[mf][r]  = lt_b ? best[mf][r] : (lt_s ? s : sec[mf][r]);
                    sidx[mf][r] = lt_b ? bidx[mf][r] : (lt_s ? code : sidx[mf][r]);
                    best[mf][r] = lt_b ? s : best[mf][r];
                    bidx[mf][r] = lt_b ? code : bidx[mf][r];
                }
        }
    }

    // cross-lane top-2 merge over the 16 col-classes (lane&15)
#pragma unroll
    for (int mf = 0; mf < 4; ++mf)
#pragma unroll
        for (int r = 0; r < 4; ++r) {
            float b = best[mf][r], sc = sec[mf][r];
            int bi = bidx[mf][r], si = sidx[mf][r];
#pragma unroll
            for (int off = 1; off < 16; off <<= 1) {
                float ob  = __shfl_xor(b, off);
                int   obi = __shfl_xor(bi, off);
                float osc = __shfl_xor(sc, off);
                int   osi = __shfl_xor(si, off);
                bool o_lt = ob < b;
                float loser  = o_lt ? b  : ob;
                int   loseri = o_lt ? bi : obi;
                b  = o_lt ? ob  : b;
                bi = o_lt ? obi : bi;
                float ns = sc; int nsi = si;
                if (osc < ns)   { ns = osc;   nsi = osi; }
                if (loser < ns) { ns = loser; nsi = loseri; }
                sc = ns; si = nsi;
            }
            best[mf][r] = b; sec[mf][r] = sc;
            bidx[mf][r] = bi; sidx[mf][r] = si;
        }

    if ((lane & 15) == 0) {
        const int rgrp = lane >> 4;   // C row = (lane>>4)*4 + reg [m89/m91]
#pragma unroll
        for (int mf = 0; mf < 4; ++mf)
#pragma unroll
            for (int r = 0; r < 4; ++r) {
                int row = rowbase + mf * 16 + rgrp * 4 + r;
                idxout[row] = (float)bidx[mf][r];
                if (sec[mf][r] - best[mf][r] <= TAU) {
                    int i1 = bidx[mf][r], i2 = sidx[mf][r];
                    int lo = min(i1, i2), hi = max(i1, i2);
                    int p = atomicAdd(amb_count, 1);
                    if (p < AMB_MAX) {
                        amb_rows[p] = row;
                        amb_cand[p] = lo | (hi << 12);
                    }
                }
            }
    }
}

// ---------------------------------------------------------------------------
// Pass B: pair-fix — ONE THREAD per flagged row, exact reference-chain
// comparison of the two fast candidates. np.argmin tie -> lower index.
// ---------------------------------------------------------------------------
__global__ __launch_bounds__(256, 4)
void vq_pairfix(const float* __restrict__ x,
                const float* __restrict__ emb,
                const float* __restrict__ bsqf,
                const int* __restrict__ amb_count,
                const int* __restrict__ amb_rows,
                const int* __restrict__ amb_cand,
                float* __restrict__ idxout) {
    int cnt = *amb_count;
    if (cnt > AMB_MAX) cnt = AMB_MAX;
    const int i = blockIdx.x * blockDim.x + threadIdx.x;
    if (i >= cnt) return;

    const int row = amb_rows[i];
    const int pk  = amb_cand[i];
    const int c1 = pk & 0xFFF;          // c1 < c2
    const int c2 = pk >> 12;

    float af[DIM];
    const float4* xr = reinterpret_cast<const float4*>(x + (size_t)row * DIM);
#pragma unroll
    for (int j = 0; j < DIM / 4; ++j) {
        float4 v = xr[j];
        af[j * 4 + 0] = v.x; af[j * 4 + 1] = v.y;
        af[j * 4 + 2] = v.z; af[j * 4 + 3] = v.w;
    }
    const float a_sq = np_pairwise_sq64(af);

    float d1 = np_dist(af, a_sq, emb + (size_t)c1 * DIM, bsqf[c1]);
    float d2 = np_dist(af, a_sq, emb + (size_t)c2 * DIM, bsqf[c2]);
    idxout[row] = (float)((d2 < d1) ? c2 : c1);   // tie -> lower index (c1)
}

// ---------------------------------------------------------------------------
// Pass C: finalize — gather quantized rows, histogram, deterministic loss.
// ---------------------------------------------------------------------------
__global__ __launch_bounds__(BLOCKC, 2)
void vq_finalize(const float* __restrict__ x,
                 const float* __restrict__ emb,
                 const float* __restrict__ idxout,
                 float* __restrict__ qout,
                 int* __restrict__ hist,
                 float* __restrict__ partials) {
    __shared__ float red[BLOCKC];
    const int row = blockIdx.x * BLOCKC + threadIdx.x;
    const int k = (int)idxout[row];

    const float4* xr = reinterpret_cast<const float4*>(x + (size_t)row * DIM);
    const float4* q  = reinterpret_cast<const float4*>(emb + (size_t)k * DIM);
    float4* qo = reinterpret_cast<float4*>(qout + (size_t)row * DIM);

    float lsum0 = 0.f, lsum1 = 0.f;
#pragma unroll
    for (int i = 0; i < DIM / 4; ++i) {
        float4 v = q[i];
        float4 a = xr[i];
        qo[i] = v;
        float dx = v.x - a.x, dy = v.y - a.y;
        float dz = v.z - a.z, dw = v.w - a.w;
        lsum0 = fmaf(dx, dx, lsum0);
        lsum1 = fmaf(dy, dy, lsum1);
        lsum0 = fmaf(dz, dz, lsum0);
        lsum1 = fmaf(dw, dw, lsum1);
    }
    atomicAdd(&hist[k], 1);

    __syncthreads();
    red[threadIdx.x] = lsum0 + lsum1;
    __syncthreads();
    for (int off = BLOCKC / 2; off > 0; off >>= 1) {
        if (threadIdx.x < off) red[threadIdx.x] += red[threadIdx.x + off];
        __syncthreads();
    }
    if (threadIdx.x == 0) partials[blockIdx.x] = red[0];
}

// ---------------------------------------------------------------------------
// Final: perplexity (fp64) + loss reduction.
// ---------------------------------------------------------------------------
__global__ void vq_final(const int* __restrict__ hist,
                         const float* __restrict__ partials,
                         float* __restrict__ out2) {
    __shared__ double sh[KCODES];
    __shared__ float sl[NBLOCKC];
    int t = threadIdx.x;

    double p = (double)hist[t] * (1.0 / (double)N_ROWS);
    sh[t] = p * log(p + 1e-10);
    if (t < NBLOCKC) sl[t] = partials[t];
    __syncthreads();

    for (int off = KCODES / 2; off > 0; off >>= 1) {
        if (t < off) sh[t] += sh[t + off];
        __syncthreads();
    }
    for (int off = NBLOCKC / 2; off > 0; off >>= 1) {
        if (t < off) sl[t] += sl[t + off];
        __syncthreads();
    }
    if (t == 0) {
        out2[0] = (float)exp(-sh[0]);
        out2[1] = 1.25f * sl[0] * (1.0f / (float)(N_ROWS * DIM));
    }
}

// ---------------------------------------------------------------------------
extern "C" void kernel_launch(void* const* d_in, const int* in_sizes, int n_in,
                              void* d_out, int out_size, void* d_ws, size_t ws_size,
                              hipStream_t stream) {
    const float* x   = (const float*)d_in[0];   // [131072, 64]
    const float* emb = (const float*)d_in[1];   // [1024, 64]
    float* out = (float*)d_out;

    // ws: hist[1024]@0 | bsqf@4096 | partials@8192 | amb_count@10240 |
    //     amb_rows[32768]@12288 | amb_cand[32768]@143360 | epack@274432 (256KB)
    int*   hist      = (int*)d_ws;
    float* bsqf      = (float*)((char*)d_ws + 4096);
    float* partials  = (float*)((char*)d_ws + 8192);
    int*   amb_count = (int*)((char*)d_ws + 10240);
    int*   amb_rows  = (int*)((char*)d_ws + 12288);
    int*   amb_cand  = (int*)((char*)d_ws + 143360);
    unsigned short* epack = (unsigned short*)((char*)d_ws + 274432);

    float* qout    = out;                       // 8388608
    float* idxout  = out + 8388608;             // 131072
    float* scalars = out + 8388608 + 131072;    // perplexity, vq_loss

    vq_prep    <<<KCODES / 256, 256, 0, stream>>>(emb, hist, bsqf, amb_count, epack);
    vq_fast    <<<N_ROWS / 256, 256, 0, stream>>>(x, epack, bsqf, idxout, amb_count,
                                                  amb_rows, amb_cand);
    vq_pairfix <<<AMB_MAX / 256, 256, 0, stream>>>(x, emb, bsqf, amb_count,
                                                   amb_rows, amb_cand, idxout);
    vq_finalize<<<NBLOCKC, BLOCKC, 0, stream>>>(x, emb, idxout, qout, hist, partials);
    vq_final   <<<1, KCODES, 0, stream>>>(hist, partials, scalars);
}

// Round 8
// 129.575 us; speedup vs baseline: 3.4464x; 1.0533x over previous
//
#include <hip/hip_runtime.h>
#include <float.h>

#define N_ROWS 131072
#define DIM 64
#define KCODES 1024
#define TAU 1.0e-3f
#define AMB_MAX 32768
#define BLOCKC 256
#define NBLOCKC (N_ROWS / BLOCKC)   // 512
#define NBLOCKA (N_ROWS / 128)      // 1024 blocks, 4 waves x 32 rows each

typedef __attribute__((ext_vector_type(8))) short short8;
typedef __attribute__((ext_vector_type(4))) float f32x4;

// bf16 round-to-nearest-even split helpers
__device__ __forceinline__ unsigned short f2bf_rne(float x) {
    unsigned int u = __float_as_uint(x);
    unsigned int r = u + 0x7FFFu + ((u >> 16) & 1u);
    return (unsigned short)(r >> 16);
}
__device__ __forceinline__ float bf2f(unsigned short h) {
    return __uint_as_float(((unsigned int)h) << 16);
}

// numpy pairwise sum of squares over 64 floats (bit-exact vs np.sum(v*v))
__device__ __forceinline__ float np_pairwise_sq64(const float* v) {
    float r[8];
#pragma unroll
    for (int j = 0; j < 8; ++j) r[j] = __fmul_rn(v[j], v[j]);
#pragma unroll
    for (int i = 8; i < 64; i += 8)
#pragma unroll
        for (int j = 0; j < 8; ++j)
            r[j] = __fadd_rn(r[j], __fmul_rn(v[i + j], v[i + j]));
    return __fadd_rn(
        __fadd_rn(__fadd_rn(r[0], r[1]), __fadd_rn(r[2], r[3])),
        __fadd_rn(__fadd_rn(r[4], r[5]), __fadd_rn(r[6], r[7])));
}

// exact reference-chain distance for one (row, code):
// d = fl32( fl32(a_sq - fl32(2*dot_f64)) + b_sq )   [validated rounds 3-7]
__device__ __forceinline__ float np_dist(const float* af, float a_sq,
                                         const float* e, float bq) {
    double acc0 = 0.0, acc1 = 0.0, acc2 = 0.0, acc3 = 0.0;
#pragma unroll
    for (int d = 0; d < DIM; d += 4) {
        float4 ev = *reinterpret_cast<const float4*>(e + d);
        acc0 = fma((double)af[d + 0], (double)ev.x, acc0);
        acc1 = fma((double)af[d + 1], (double)ev.y, acc1);
        acc2 = fma((double)af[d + 2], (double)ev.z, acc2);
        acc3 = fma((double)af[d + 3], (double)ev.w, acc3);
    }
    double dot = (acc0 + acc1) + (acc2 + acc3);
    float ab = (float)(2.0 * dot);
    return __fadd_rn(__fsub_rn(a_sq, ab), bq);
}

// ---------------------------------------------------------------------------
// Prep: zero hist/amb, np-exact b_sq, pack E as bf16 hi/lo in MFMA frag order:
// epack[ct(64)][lvl(2)][kt(2)][lane(64)][j(8)] ushort.
// ---------------------------------------------------------------------------
__global__ void vq_prep(const float* __restrict__ emb,
                        int* __restrict__ hist,
                        float* __restrict__ bsqf,
                        int* __restrict__ amb_count,
                        unsigned short* __restrict__ epack) {
    int c = blockIdx.x * blockDim.x + threadIdx.x;   // 0..1023
    if (c == 0) *amb_count = 0;
    if (c >= KCODES) return;
    hist[c] = 0;
    float e[DIM];
    const float4* src = reinterpret_cast<const float4*>(emb + (size_t)c * DIM);
#pragma unroll
    for (int i = 0; i < DIM / 4; ++i) {
        float4 v = src[i];
        e[i * 4 + 0] = v.x; e[i * 4 + 1] = v.y;
        e[i * 4 + 2] = v.z; e[i * 4 + 3] = v.w;
    }
    bsqf[c] = np_pairwise_sq64(e);

    const int ct = c >> 4, col = c & 15;
#pragma unroll
    for (int k = 0; k < DIM; ++k) {
        unsigned short h = f2bf_rne(e[k]);
        unsigned short l = f2bf_rne(e[k] - bf2f(h));
        int kt = k >> 5;
        int lane = (((k & 31) >> 3) << 4) | col;
        int j = k & 7;
        epack[(((size_t)(ct * 2 + 0) * 2 + kt) * 64 + lane) * 8 + j] = h;
        epack[(((size_t)(ct * 2 + 1) * 2 + kt) * 64 + lane) * 8 + j] = l;
    }
}

// ---------------------------------------------------------------------------
// Pass A: MFMA scorer. Wave owns 32 rows (2 M-frags); 8 x 32KB LDS chunks;
// bsq table staged in LDS. Tracks best+second (values & indices); flagged
// rows (gap <= TAU) emit candidate pair for the exact pair-fix.
// ---------------------------------------------------------------------------
__global__ __launch_bounds__(256, 4)
void vq_fast(const float* __restrict__ x,
             const unsigned short* __restrict__ epack,
             const float* __restrict__ bsqf,
             float* __restrict__ idxout,
             int* __restrict__ amb_count,
             int* __restrict__ amb_rows,
             int* __restrict__ amb_cand) {
    __shared__ unsigned short lds[16384];   // 32 KiB = 8 code-tiles
    __shared__ float bql[KCODES];           // 4 KiB bsq table

    const int t = threadIdx.x;
    const int lane = t & 63;
    const int wid = t >> 6;
    const int rowbase = blockIdx.x * 128 + wid * 32;
    const int arow = lane & 15;
    const int kgrp = lane >> 4;

    // stage bsq table (read after the first barrier below)
#pragma unroll
    for (int i = 0; i < 4; ++i) bql[t + i * 256] = bsqf[t + i * 256];

    // A-frags: 2 M-frags x 2 k-tiles, hi+lo
    short8 ah[2][2], al[2][2];
#pragma unroll
    for (int mf = 0; mf < 2; ++mf) {
#pragma unroll
        for (int kt = 0; kt < 2; ++kt) {
            const float* src = x + (size_t)(rowbase + mf * 16 + arow) * DIM + kt * 32 + kgrp * 8;
            float4 v0 = *reinterpret_cast<const float4*>(src);
            float4 v1 = *reinterpret_cast<const float4*>(src + 4);
            float xv[8] = {v0.x, v0.y, v0.z, v0.w, v1.x, v1.y, v1.z, v1.w};
            short8 h, l;
#pragma unroll
            for (int j = 0; j < 8; ++j) {
                unsigned short hh = f2bf_rne(xv[j]);
                h[j] = (short)hh;
                l[j] = (short)f2bf_rne(xv[j] - bf2f(hh));
            }
            ah[mf][kt] = h;
            al[mf][kt] = l;
        }
    }

    float best[2][4], sec[2][4];
    int bidx[2][4], sidx[2][4];
#pragma unroll
    for (int mf = 0; mf < 2; ++mf)
#pragma unroll
        for (int r = 0; r < 4; ++r) {
            best[mf][r] = FLT_MAX; sec[mf][r] = FLT_MAX;
            bidx[mf][r] = 0; sidx[mf][r] = 0;
        }

    for (int ch = 0; ch < 8; ++ch) {
        __syncthreads();
        {   // stage 32KB chunk: 2048 float4, 8 per thread, coalesced
            const float4* gsrc = reinterpret_cast<const float4*>(epack + (size_t)ch * 16384);
            float4* ldst = reinterpret_cast<float4*>(lds);
#pragma unroll
            for (int i = 0; i < 8; ++i)
                ldst[t + i * 256] = gsrc[t + i * 256];
        }
        __syncthreads();

        for (int ctl = 0; ctl < 8; ++ctl) {
            const int code0 = (ch * 8 + ctl) * 16;
            const unsigned short* fb = lds + ctl * 2048 + lane * 8;
            short8 bh0 = *reinterpret_cast<const short8*>(fb + 0 * 512);
            short8 bh1 = *reinterpret_cast<const short8*>(fb + 1 * 512);
            short8 bl0 = *reinterpret_cast<const short8*>(fb + 2 * 512);
            short8 bl1 = *reinterpret_cast<const short8*>(fb + 3 * 512);
            const float bq = bql[code0 + arow];   // LDS broadcast, no VMEM

            f32x4 acc[2];
#pragma unroll
            for (int mf = 0; mf < 2; ++mf) {
                f32x4 a = {0.f, 0.f, 0.f, 0.f};
                a = __builtin_amdgcn_mfma_f32_16x16x32_bf16(ah[mf][0], bh0, a, 0, 0, 0);
                a = __builtin_amdgcn_mfma_f32_16x16x32_bf16(ah[mf][1], bh1, a, 0, 0, 0);
                a = __builtin_amdgcn_mfma_f32_16x16x32_bf16(ah[mf][0], bl0, a, 0, 0, 0);
                a = __builtin_amdgcn_mfma_f32_16x16x32_bf16(ah[mf][1], bl1, a, 0, 0, 0);
                a = __builtin_amdgcn_mfma_f32_16x16x32_bf16(al[mf][0], bh0, a, 0, 0, 0);
                a = __builtin_amdgcn_mfma_f32_16x16x32_bf16(al[mf][1], bh1, a, 0, 0, 0);
                acc[mf] = a;
            }

            const int code = code0 + arow;   // C col = lane&15 [m89/m91]
#pragma unroll
            for (int mf = 0; mf < 2; ++mf)
#pragma unroll
                for (int r = 0; r < 4; ++r) {
                    float s = fmaf(-2.0f, acc[mf][r], bq);
                    bool lt_b = s < best[mf][r];
                    bool lt_s = s < sec[mf][r];
                    sec[mf][r]  = lt_b ? best[mf][r] : (lt_s ? s : sec[mf][r]);
                    sidx[mf][r] = lt_b ? bidx[mf][r] : (lt_s ? code : sidx[mf][r]);
                    best[mf][r] = lt_b ? s : best[mf][r];
                    bidx[mf][r] = lt_b ? code : bidx[mf][r];
                }
        }
    }

    // cross-lane top-2 merge over the 16 col-classes (lane&15)
#pragma unroll
    for (int mf = 0; mf < 2; ++mf)
#pragma unroll
        for (int r = 0; r < 4; ++r) {
            float b = best[mf][r], sc = sec[mf][r];
            int bi = bidx[mf][r], si = sidx[mf][r];
#pragma unroll
            for (int off = 1; off < 16; off <<= 1) {
                float ob  = __shfl_xor(b, off);
                int   obi = __shfl_xor(bi, off);
                float osc = __shfl_xor(sc, off);
                int   osi = __shfl_xor(si, off);
                bool o_lt = ob < b;
                float loser  = o_lt ? b  : ob;
                int   loseri = o_lt ? bi : obi;
                b  = o_lt ? ob  : b;
                bi = o_lt ? obi : bi;
                float ns = sc; int nsi = si;
                if (osc < ns)   { ns = osc;   nsi = osi; }
                if (loser < ns) { ns = loser; nsi = loseri; }
                sc = ns; si = nsi;
            }
            best[mf][r] = b; sec[mf][r] = sc;
            bidx[mf][r] = bi; sidx[mf][r] = si;
        }

    if ((lane & 15) == 0) {
        const int rgrp = lane >> 4;   // C row = (lane>>4)*4 + reg [m89/m91]
#pragma unroll
        for (int mf = 0; mf < 2; ++mf)
#pragma unroll
            for (int r = 0; r < 4; ++r) {
                int row = rowbase + mf * 16 + rgrp * 4 + r;
                idxout[row] = (float)bidx[mf][r];
                if (sec[mf][r] - best[mf][r] <= TAU) {
                    int i1 = bidx[mf][r], i2 = sidx[mf][r];
                    int lo = min(i1, i2), hi = max(i1, i2);
                    int p = atomicAdd(amb_count, 1);
                    if (p < AMB_MAX) {
                        amb_rows[p] = row;
                        amb_cand[p] = lo | (hi << 12);
                    }
                }
            }
    }
}

// ---------------------------------------------------------------------------
// Pass B: pair-fix — ONE THREAD per flagged row, exact reference-chain
// comparison of the two fast candidates. np.argmin tie -> lower index.
// ---------------------------------------------------------------------------
__global__ __launch_bounds__(256, 4)
void vq_pairfix(const float* __restrict__ x,
                const float* __restrict__ emb,
                const float* __restrict__ bsqf,
                const int* __restrict__ amb_count,
                const int* __restrict__ amb_rows,
                const int* __restrict__ amb_cand,
                float* __restrict__ idxout) {
    int cnt = *amb_count;
    if (cnt > AMB_MAX) cnt = AMB_MAX;
    const int i = blockIdx.x * blockDim.x + threadIdx.x;
    if (i >= cnt) return;

    const int row = amb_rows[i];
    const int pk  = amb_cand[i];
    const int c1 = pk & 0xFFF;          // c1 < c2
    const int c2 = pk >> 12;

    float af[DIM];
    const float4* xr = reinterpret_cast<const float4*>(x + (size_t)row * DIM);
#pragma unroll
    for (int j = 0; j < DIM / 4; ++j) {
        float4 v = xr[j];
        af[j * 4 + 0] = v.x; af[j * 4 + 1] = v.y;
        af[j * 4 + 2] = v.z; af[j * 4 + 3] = v.w;
    }
    const float a_sq = np_pairwise_sq64(af);

    float d1 = np_dist(af, a_sq, emb + (size_t)c1 * DIM, bsqf[c1]);
    float d2 = np_dist(af, a_sq, emb + (size_t)c2 * DIM, bsqf[c2]);
    idxout[row] = (float)((d2 < d1) ? c2 : c1);   // tie -> lower index (c1)
}

// ---------------------------------------------------------------------------
// Pass C: finalize — gather quantized rows, histogram, deterministic loss.
// ---------------------------------------------------------------------------
__global__ __launch_bounds__(BLOCKC, 2)
void vq_finalize(const float* __restrict__ x,
                 const float* __restrict__ emb,
                 const float* __restrict__ idxout,
                 float* __restrict__ qout,
                 int* __restrict__ hist,
                 float* __restrict__ partials) {
    __shared__ float red[BLOCKC];
    const int row = blockIdx.x * BLOCKC + threadIdx.x;
    const int k = (int)idxout[row];

    const float4* xr = reinterpret_cast<const float4*>(x + (size_t)row * DIM);
    const float4* q  = reinterpret_cast<const float4*>(emb + (size_t)k * DIM);
    float4* qo = reinterpret_cast<float4*>(qout + (size_t)row * DIM);

    float lsum0 = 0.f, lsum1 = 0.f;
#pragma unroll
    for (int i = 0; i < DIM / 4; ++i) {
        float4 v = q[i];
        float4 a = xr[i];
        qo[i] = v;
        float dx = v.x - a.x, dy = v.y - a.y;
        float dz = v.z - a.z, dw = v.w - a.w;
        lsum0 = fmaf(dx, dx, lsum0);
        lsum1 = fmaf(dy, dy, lsum1);
        lsum0 = fmaf(dz, dz, lsum0);
        lsum1 = fmaf(dw, dw, lsum1);
    }
    atomicAdd(&hist[k], 1);

    __syncthreads();
    red[threadIdx.x] = lsum0 + lsum1;
    __syncthreads();
    for (int off = BLOCKC / 2; off > 0; off >>= 1) {
        if (threadIdx.x < off) red[threadIdx.x] += red[threadIdx.x + off];
        __syncthreads();
    }
    if (threadIdx.x == 0) partials[blockIdx.x] = red[0];
}

// ---------------------------------------------------------------------------
// Final: perplexity (fp64) + loss reduction.
// ---------------------------------------------------------------------------
__global__ void vq_final(const int* __restrict__ hist,
                         const float* __restrict__ partials,
                         float* __restrict__ out2) {
    __shared__ double sh[KCODES];
    __shared__ float sl[NBLOCKC];
    int t = threadIdx.x;

    double p = (double)hist[t] * (1.0 / (double)N_ROWS);
    sh[t] = p * log(p + 1e-10);
    if (t < NBLOCKC) sl[t] = partials[t];
    __syncthreads();

    for (int off = KCODES / 2; off > 0; off >>= 1) {
        if (t < off) sh[t] += sh[t + off];
        __syncthreads();
    }
    for (int off = NBLOCKC / 2; off > 0; off >>= 1) {
        if (t < off) sl[t] += sl[t + off];
        __syncthreads();
    }
    if (t == 0) {
        out2[0] = (float)exp(-sh[0]);
        out2[1] = 1.25f * sl[0] * (1.0f / (float)(N_ROWS * DIM));
    }
}

// ---------------------------------------------------------------------------
extern "C" void kernel_launch(void* const* d_in, const int* in_sizes, int n_in,
                              void* d_out, int out_size, void* d_ws, size_t ws_size,
                              hipStream_t stream) {
    const float* x   = (const float*)d_in[0];   // [131072, 64]
    const float* emb = (const float*)d_in[1];   // [1024, 64]
    float* out = (float*)d_out;

    // ws: hist[1024]@0 | bsqf@4096 | partials@8192 | amb_count@10240 |
    //     amb_rows[32768]@12288 | amb_cand[32768]@143360 | epack@274432 (256KB)
    int*   hist      = (int*)d_ws;
    float* bsqf      = (float*)((char*)d_ws + 4096);
    float* partials  = (float*)((char*)d_ws + 8192);
    int*   amb_count = (int*)((char*)d_ws + 10240);
    int*   amb_rows  = (int*)((char*)d_ws + 12288);
    int*   amb_cand  = (int*)((char*)d_ws + 143360);
    unsigned short* epack = (unsigned short*)((char*)d_ws + 274432);

    float* qout    = out;                       // 8388608
    float* idxout  = out + 8388608;             // 131072
    float* scalars = out + 8388608 + 131072;    // perplexity, vq_loss

    vq_prep    <<<KCODES / 256, 256, 0, stream>>>(emb, hist, bsqf, amb_count, epack);
    vq_fast    <<<NBLOCKA, 256, 0, stream>>>(x, epack, bsqf, idxout, amb_count,
                                             amb_rows, amb_cand);
    vq_pairfix <<<AMB_MAX / 256, 256, 0, stream>>>(x, emb, bsqf, amb_count,
                                                   amb_rows, amb_cand, idxout);
    vq_finalize<<<NBLOCKC, BLOCKC, 0, stream>>>(x, emb, idxout, qout, hist, partials);
    vq_final   <<<1, KCODES, 0, stream>>>(hist, partials, scalars);
}